// Round 10
// baseline (271.434 us; speedup 1.0000x reference)
//
#include <hip/hip_runtime.h>
#include <math.h>

#define B_ 8
#define T_ 1024
#define F_ 256
#define H_ 256
#define BT_ (B_*T_)          // 8192
constexpr float EPS = 1e-5f;
constexpr float SCALE = 0.0625f;        // 1/sqrt(256), folded into qbuf

typedef unsigned int u32;
typedef unsigned short u16;
typedef __attribute__((ext_vector_type(8))) short bf16x8;    // 8 bf16 = 4 VGPRs
typedef __attribute__((ext_vector_type(4))) float f32x4;
typedef __attribute__((ext_vector_type(16))) float f32x16;
typedef __attribute__((ext_vector_type(4))) u32 u32x4;

// ---------- bf16 helpers ----------
__device__ __forceinline__ float bf1(u16 p) { return __uint_as_float(((u32)p) << 16); }
__device__ __forceinline__ u16 f2bf(float f) {
  u32 u = __float_as_uint(f);
  u32 r = u + 0x7FFFu + ((u >> 16) & 1u);   // RNE
  return (u16)(r >> 16);
}
__device__ __forceinline__ u32 pk2(float lo, float hi2) {
  return (u32)f2bf(lo) | ((u32)f2bf(hi2) << 16);
}

__device__ __forceinline__ f32x4 mfma16(bf16x8 a, bf16x8 b, f32x4 c) {
  return __builtin_amdgcn_mfma_f32_16x16x32_bf16(a, b, c, 0, 0, 0);
}
__device__ __forceinline__ f32x16 mfma32(bf16x8 a, bf16x8 b, f32x16 c) {
  return __builtin_amdgcn_mfma_f32_32x32x16_bf16(a, b, c, 0, 0, 0);
}

// async global->LDS, 16B per lane; dest = wave-uniform base + lane*16
__device__ __forceinline__ void gload_lds16(const u16* g, u16* l) {
  __builtin_amdgcn_global_load_lds(
      (const __attribute__((address_space(1))) u32*)(uintptr_t)g,
      (__attribute__((address_space(3))) u32*)(u32)(uintptr_t)l,
      16, 0, 0);
}

// raw barrier bracketed by sched fences (raw s_barrier does NOT drain counters)
__device__ __forceinline__ void bar() {
  __builtin_amdgcn_sched_barrier(0);
  __builtin_amdgcn_s_barrier();
  __builtin_amdgcn_sched_barrier(0);
}

// ---------- K1: fused prologue ----------
// blocks [0,2048): LayerNorm over F, wave-per-row (barrier-free, no LDS).
// blocks [2048,2432): weight prep transpose W[z][f][h] f32 -> wT[z][h][f] bf16.
__global__ __launch_bounds__(256) void prologue_kernel(
    const float* __restrict__ x, const float* __restrict__ w, const float* __restrict__ bi,
    u16* __restrict__ xnr, u16* __restrict__ xni,
    const float* __restrict__ Wq, const float* __restrict__ Wk, const float* __restrict__ Wv,
    u16* __restrict__ wT) {
  const int tid = threadIdx.x;
  if (blockIdx.x < 2048) {
    // ---- ln1: one row per wave ----
    const int wid = tid >> 6, lane = tid & 63;
    const int row = blockIdx.x * 4 + wid;
    const float2* xr = reinterpret_cast<const float2*>(x) + (size_t)row * F_;
    float2 xv[4];
    float sr = 0.f, si = 0.f, sr2 = 0.f, si2 = 0.f;
    #pragma unroll
    for (int j = 0; j < 4; j++) {
      xv[j] = xr[lane * 4 + j];
      sr += xv[j].x; si += xv[j].y;
      sr2 += xv[j].x * xv[j].x; si2 += xv[j].y * xv[j].y;
    }
    #pragma unroll
    for (int off = 32; off > 0; off >>= 1) {
      sr  += __shfl_xor(sr,  off, 64);
      si  += __shfl_xor(si,  off, 64);
      sr2 += __shfl_xor(sr2, off, 64);
      si2 += __shfl_xor(si2, off, 64);
    }
    const float inv = 1.0f / F_;
    float mr = sr * inv, mi = si * inv;
    float vr = sr2 * inv - mr * mr, vi = si2 * inv - mi * mi;
    float rr = rsqrtf(vr + EPS), ri = rsqrtf(vi + EPS);
    float4 w4 = *reinterpret_cast<const float4*>(w + lane * 4);
    float4 b4 = *reinterpret_cast<const float4*>(bi + lane * 4);
    const float wj[4] = {w4.x, w4.y, w4.z, w4.w};
    const float bj[4] = {b4.x, b4.y, b4.z, b4.w};
    ushort4 outr, outi;
    u16* orp = reinterpret_cast<u16*>(&outr);
    u16* oip = reinterpret_cast<u16*>(&outi);
    #pragma unroll
    for (int j = 0; j < 4; j++) {
      orp[j] = f2bf((xv[j].x - mr) * rr * wj[j] + bj[j]);
      oip[j] = f2bf((xv[j].y - mi) * ri * wj[j] + bj[j]);
    }
    *reinterpret_cast<ushort4*>(xnr + (size_t)row * F_ + lane * 4) = outr;
    *reinterpret_cast<ushort4*>(xni + (size_t)row * F_ + lane * 4) = outi;
  } else {
    // ---- wprep: 384 blocks, z = idx/16, 64x64 tile (ft,ht) = idx%16 ----
    const int idx = blockIdx.x - 2048;
    const int z = idx >> 4, rem = idx & 15;
    const int m = z >> 3, n = z & 7;
    const float* W = (m == 0 ? Wq : (m == 1 ? Wk : Wv)) + (size_t)n * F_ * H_;
    const int ft = (rem & 3) * 64;
    const int ht = (rem >> 2) * 64;
    __shared__ __align__(16) u16 Ts[64][72];
    #pragma unroll
    for (int i = 0; i < 4; i++) {
      int id = tid + i * 256;
      int r = id >> 4, c4 = (id & 15) * 4;
      float4 p = *reinterpret_cast<const float4*>(&W[(size_t)(ft + r) * H_ + ht + c4]);
      Ts[r][c4 + 0] = f2bf(p.x); Ts[r][c4 + 1] = f2bf(p.y);
      Ts[r][c4 + 2] = f2bf(p.z); Ts[r][c4 + 3] = f2bf(p.w);
    }
    __syncthreads();
    u16* op = wT + (size_t)z * F_ * H_ + (size_t)ht * F_ + ft;
    #pragma unroll
    for (int i = 0; i < 2; i++) {
      int id = tid + i * 256;
      int hl = id & 63, g = id >> 6;
      u16 tmp[8];
      #pragma unroll
      for (int j = 0; j < 8; j++) tmp[j] = Ts[g * 8 + j][hl];
      *reinterpret_cast<uint4*>(op + (size_t)hl * F_ + g * 8) =
          *reinterpret_cast<const uint4*>(tmp);
    }
  }
}

// ---------- K2: QKV projections — 512-thr, 256x256 tile, BK=64, 4 fat K-steps ----------
// (byte-identical to R8)
__global__ __launch_bounds__(512, 2) void qkv_kernel(
    const u16* __restrict__ xnr, const u16* __restrict__ xni, const u16* __restrict__ wT,
    const float* __restrict__ bq, const float* __restrict__ bk, const float* __restrict__ bv,
    u16* __restrict__ qo, u16* __restrict__ ko, u16* __restrict__ vTo) {
  const int z = blockIdx.y;
  const int m = z >> 3, n = z & 7;
  int sel; const float* bias; u16* out;
  if (m == 0)      { sel = (n >> 1) & 1;  bias = bq; out = qo + (size_t)n * BT_ * H_; }
  else if (m == 1) { sel = n & 1;         bias = bk; out = ko + (size_t)n * BT_ * H_; }
  else             { sel = __popc(n) & 1; bias = bv; out = nullptr; }
  const float osc = (m == 0) ? SCALE : 1.0f;
  const u16* A = sel ? xni : xnr;
  const u16* wp = wT + (size_t)z * F_ * H_;
  bias += n * H_;
  const int rowbase = blockIdx.x * 256;

  __shared__ __align__(16) u16 Sh[65536];         // 128 KB flat

  const int tid = threadIdx.x;                    // 0..511
  const int wv = tid >> 6, lane = tid & 63;
  const int quad = lane >> 4, l16 = lane & 15;
  const int wrow = wv >> 2, wcol = wv & 3;        // 2x4 wave grid; tile 128x64

  f32x4 acc[8][4];
  #pragma unroll
  for (int i = 0; i < 8; i++)
    #pragma unroll
    for (int j = 0; j < 4; j++) acc[i][j] = (f32x4){0.f, 0.f, 0.f, 0.f};

  const int r8 = tid >> 3;                        // staging row 0..63 (per instr)
  const int usw = ((tid & 7) ^ (r8 & 7)) * 8;     // source pre-swizzle (8 units/row)

  auto stage = [&](int s, int buf) {              // step s: kb = s*64
    const int kb = s * 64;
    #pragma unroll
    for (int c = 0; c < 4; c++) {
      gload_lds16(A + (size_t)(rowbase + c * 64 + r8) * F_ + kb + usw,
                  &Sh[buf * 16384 + c * 4096 + tid * 8]);
      gload_lds16(wp + (size_t)(c * 64 + r8) * F_ + kb + usw,
                  &Sh[32768 + buf * 16384 + c * 4096 + tid * 8]);
    }
  };

  stage(0, 0);
  __builtin_amdgcn_sched_barrier(0);

  const int rswb = l16 & 7;                       // read swizzle: row&7 = l16&7

  #pragma unroll 1
  for (int s = 0; s < 4; s++) {
    const int buf = s & 1;
    if (s < 3) {
      stage(s + 1, buf ^ 1);                      // 8 DMAs, stay in flight
      __builtin_amdgcn_sched_barrier(0);
      asm volatile("s_waitcnt vmcnt(8)" ::: "memory");   // drain stage(s) only
    } else {
      asm volatile("s_waitcnt vmcnt(0)" ::: "memory");
    }
    bar();                                        // all waves: buf ready

    #pragma unroll
    for (int kk = 0; kk < 2; kk++) {              // two K=32 sub-windows
      bf16x8 a[8], b[4];
      #pragma unroll
      for (int mi = 0; mi < 8; mi++) {
        int row = wrow * 128 + mi * 16 + l16;
        a[mi] = *reinterpret_cast<const bf16x8*>(
            &Sh[buf * 16384 + row * 64 + (((kk * 4 + quad) ^ rswb) << 3)]);
      }
      #pragma unroll
      for (int nj = 0; nj < 4; nj++) {
        int row = wcol * 64 + nj * 16 + l16;
        b[nj] = *reinterpret_cast<const bf16x8*>(
            &Sh[32768 + buf * 16384 + row * 64 + (((kk * 4 + quad) ^ rswb) << 3)]);
      }
      __builtin_amdgcn_s_setprio(1);
      #pragma unroll
      for (int mi = 0; mi < 8; mi++)
        #pragma unroll
        for (int nj = 0; nj < 4; nj++)
          acc[mi][nj] = mfma16(a[mi], b[nj], acc[mi][nj]);
      __builtin_amdgcn_s_setprio(0);
    }
    bar();                                        // buf reads retired -> reusable
  }

  float bias4[4];
  #pragma unroll
  for (int nj = 0; nj < 4; nj++)
    bias4[nj] = bias[wcol * 64 + nj * 16 + l16];

  if (m != 2) {   // q/k: row-major store (already coalesced along h)
    u16* Epi = Sh + wv * 1536;                    // wave-private 3KB
    #pragma unroll
    for (int mi = 0; mi < 8; mi++) {
      #pragma unroll
      for (int nj = 0; nj < 4; nj++)
        #pragma unroll
        for (int r = 0; r < 4; r++)
          Epi[(quad * 4 + r) * 72 + nj * 16 + l16] =
              f2bf((acc[mi][nj][r] + bias4[nj]) * osc);
      int row = rowbase + wrow * 128 + mi * 16 + l16;
      uint4 v0 = *reinterpret_cast<const uint4*>(&Epi[l16 * 72 + quad * 16]);
      uint4 v1 = *reinterpret_cast<const uint4*>(&Epi[l16 * 72 + quad * 16 + 8]);
      u16* op = out + (size_t)row * H_ + wcol * 64 + quad * 16;
      *reinterpret_cast<uint4*>(op) = v0;
      *reinterpret_cast<uint4*>(op + 8) = v1;
    }
  } else {        // v: [h][bt] transpose per wave, stores coalesced along bt
    u16* Epv = Sh + wv * 4608;                    // 64 x 72 u16 = 9216 B, wave-private
    #pragma unroll
    for (int hp = 0; hp < 2; hp++) {              // two 64-bt halves (mi = hp*4+mj)
      #pragma unroll
      for (int mj = 0; mj < 4; mj++)
        #pragma unroll
        for (int nj = 0; nj < 4; nj++) {
          ushort4 pv;
          u16* pp = reinterpret_cast<u16*>(&pv);
          #pragma unroll
          for (int r = 0; r < 4; r++)
            pp[r] = f2bf(acc[hp * 4 + mj][nj][r] + bias4[nj]);
          *reinterpret_cast<uint2*>(
              &Epv[(nj * 16 + l16) * 72 + mj * 16 + quad * 4]) =
              *reinterpret_cast<const uint2*>(&pv);
        }
      #pragma unroll
      for (int i = 0; i < 8; i++) {
        int hrow = i * 8 + (lane >> 3);
        uint4 vv = *reinterpret_cast<const uint4*>(
            &Epv[hrow * 72 + (lane & 7) * 8]);
        u16* op = vTo + (size_t)n * H_ * BT_ +
                  (size_t)(wcol * 64 + hrow) * BT_ +
                  rowbase + wrow * 128 + hp * 64 + (lane & 7) * 8;
        *reinterpret_cast<uint4*>(op) = vv;
      }
    }
  }
}

// ---------- K3: MFMA flash attention v6 — swapped QK^T, in-register P ----------
// v3 skeleton (barriers/staging/counted vmcnt identical, 106 µs verified) with the
// softmax path restructured:
//  * QK computes S^T via mfma32(kf, qf) (operand swap — register contents
//    unchanged): lane (hi,l32) holds S[key=kh*32+crow(r,hi)][q=qh*32+l32].
//  * P packed to bf16 in-register (pk2 = existing f2bf pair) and the PV A-frags
//    assembled via __shfl_xor(.,32) hi-half exchange. Each wave keeps its own
//    kh-half fragments in REGISTERS; only cross-kh fragments go through an 8 KB
//    Px buffer: 2 b128 writes + 2 b128 reads replace 16 scalar b16 writes +
//    4 b128 reads per wave-iter.
//  * lper is a per-lane scalar (its q=l32); one end-of-loop exchange via lsb.
//  * o/epilogue layout unchanged: C[q=crow(r,hi)][h=col] both before and after.
__global__ __launch_bounds__(256, 2) void attn_kernel(
    const u16* __restrict__ q, const u16* __restrict__ k, const u16* __restrict__ vT,
    u16* __restrict__ obuf) {
  // XCD-swizzled mapping: lin%8 = XCD; 16 consecutive slots per XCD = one nb.
  const int lin = blockIdx.y * 16 + blockIdx.x;   // 0..1023
  const int qt  = (lin >> 3) & 15;                // q-tile: 64 query rows
  const int nb  = (lin & 7) | ((lin >> 7) << 3);  // n*8 + b
  const int n = nb >> 3, b = nb & 7;
  const int tid = threadIdx.x;
  const int wv = tid >> 6, lane = tid & 63;
  const int hi = lane >> 5, l32 = lane & 31;
  const int qh = wv >> 1;            // q-half (32 rows)
  const int kh = wv & 1;             // QK: key-half (32 keys)
  const int hh = wv & 1;             // PV: h-half (128 h)

  const size_t base = (size_t)nb * T_ * H_;
  const u16* qp = q + base;          // pre-scaled by SCALE
  const u16* kp = k + base;
  const u16* vtp = vT + ((size_t)n * H_ * B_ + b) * T_;

  __shared__ __align__(16) u16 Ks[64 * 256];   // 32 KB, row-linear, XOR-swizzled units
  __shared__ __align__(16) u16 Vs[256 * 64];   // 32 KB, [h][key], XOR-swizzled units
  __shared__ __align__(16) u16 Px[2 * 2 * 2 * 64 * 8];  // 8 KB: [qh][kh][s][lane][8]
  __shared__ float lsb[128];                   // [qh][kh][q32] l-sums

  const int sr = tid >> 5, su = tid & 31;      // K DMA map

  auto stage_k = [&](int kt) {
    #pragma unroll
    for (int i = 0; i < 8; i++) {
      int row = i * 8 + sr;
      gload_lds16(kp + (size_t)(kt * 64 + row) * H_ + ((su ^ (row & 7)) * 8),
                  &Ks[i * 2048 + tid * 8]);
    }
  };
  auto stage_v = [&](int kt) {
    #pragma unroll
    for (int i = 0; i < 8; i++) {
      int g = (wv * 8 + i) * 64 + lane;        // 16B-unit index 0..2047
      int row = g >> 3, u = g & 7;             // 8 rows x 8 units / wave-instr
      gload_lds16(vtp + (size_t)row * BT_ + kt * 64 + ((u ^ (row & 7)) * 8),
                  &Vs[g * 8]);
    }
  };

  // prologue: K0 then V0 in flight
  stage_k(0);
  stage_v(0);

  const int qrow0 = qt * 64 + qh * 32;
  bf16x8 qf[16];
  #pragma unroll
  for (int kc = 0; kc < 16; kc++)
    qf[kc] = *reinterpret_cast<const bf16x8*>(
        qp + (size_t)(qrow0 + l32) * H_ + kc * 16 + hi * 8);

  f32x16 o[4];
  #pragma unroll
  for (int ot = 0; ot < 4; ot++)
    #pragma unroll
    for (int r = 0; r < 16; r++) o[ot][r] = 0.f;
  float lper = 0.f;                  // scalar: q = qh*32+l32, this wave's 32 keys

  const int krow = kh * 32 + l32;
  const int kswz = l32 & 7;
  // Px slot bases (u16 index; 512 u16 per [qh][kh][s] slab)
  u16* px_own = &Px[(((qh * 2 + kh) * 2 + 0) * 64 + lane) * 8];
  const u16* px_par0 = &Px[(((qh * 2 + (1 - kh)) * 2 + 0) * 64 + lane) * 8];
  const u16* px_par1 = &Px[(((qh * 2 + (1 - kh)) * 2 + 1) * 64 + lane) * 8];

  #pragma unroll 1
  for (int kt = 0; kt < 16; kt++) {
    // K(kt) landed (own 8 newest outstanding are V(kt))
    asm volatile("s_waitcnt vmcnt(8)" ::: "memory");
    bar();

    // ---- QK^T (swapped): S^T[key][q] ----
    f32x16 sa, sb;
    #pragma unroll
    for (int r = 0; r < 16; r++) { sa[r] = 0.f; sb[r] = 0.f; }
    __builtin_amdgcn_s_setprio(1);
    #pragma unroll
    for (int kc = 0; kc < 16; kc += 2) {
      bf16x8 kfa = *reinterpret_cast<const bf16x8*>(
          &Ks[(krow << 8) + ((((kc)     * 2 + hi) ^ kswz) << 3)]);
      bf16x8 kfb = *reinterpret_cast<const bf16x8*>(
          &Ks[(krow << 8) + ((((kc + 1) * 2 + hi) ^ kswz) << 3)]);
      sa = mfma32(kfa, qf[kc], sa);
      sb = mfma32(kfb, qf[kc + 1], sb);
    }
    __builtin_amdgcn_s_setprio(0);

    // ---- softmax partials, fully in-register ----
    float p[16];
    #pragma unroll
    for (int r = 0; r < 16; r++) {
      p[r] = __expf(sa[r] + sb[r]);
      lper += p[r];
    }
    // pack to bf16 words and assemble PV A-fragments (keys ascending):
    // lane (hi,l32) holds half-local keys crow(r,hi)=(r&3)+8*(r>>2)+4*hi.
    // frag s needs keys s*16 + hi*8 .. +8.
    u32 W0[4], W1[4];
    {
      u32 A0 = pk2(p[0], p[1]),  A1 = pk2(p[2], p[3]);
      u32 B0 = pk2(p[4], p[5]),  B1 = pk2(p[6], p[7]);
      u32 xA0 = (u32)__shfl_xor((int)A0, 32, 64);
      u32 xA1 = (u32)__shfl_xor((int)A1, 32, 64);
      u32 xB0 = (u32)__shfl_xor((int)B0, 32, 64);
      u32 xB1 = (u32)__shfl_xor((int)B1, 32, 64);
      W0[0] = hi ? xB0 : A0;  W0[1] = hi ? xB1 : A1;
      W0[2] = hi ? B0 : xA0;  W0[3] = hi ? B1 : xA1;
    }
    {
      u32 A0 = pk2(p[8], p[9]),   A1 = pk2(p[10], p[11]);
      u32 B0 = pk2(p[12], p[13]), B1 = pk2(p[14], p[15]);
      u32 xA0 = (u32)__shfl_xor((int)A0, 32, 64);
      u32 xA1 = (u32)__shfl_xor((int)A1, 32, 64);
      u32 xB0 = (u32)__shfl_xor((int)B0, 32, 64);
      u32 xB1 = (u32)__shfl_xor((int)B1, 32, 64);
      W1[0] = hi ? xB0 : A0;  W1[1] = hi ? xB1 : A1;
      W1[2] = hi ? B0 : xA0;  W1[3] = hi ? B1 : xA1;
    }
    u32x4 f0 = {W0[0], W0[1], W0[2], W0[3]};
    u32x4 f1 = {W1[0], W1[1], W1[2], W1[3]};
    // share cross-kh fragments through Px
    *reinterpret_cast<u32x4*>(px_own)       = f0;
    *reinterpret_cast<u32x4*>(px_own + 512) = f1;   // s=1 slab is +512 u16
    // Px/Ks traffic drained + V(kt) landed; barrier -> PV inputs ready
    asm volatile("s_waitcnt vmcnt(0) lgkmcnt(0)" ::: "memory");
    bar();

    // ---- K DMA for kt+1: latency hidden under PV ----
    if (kt < 15) stage_k(kt + 1);

    // ---- PV: own P-frags from registers, partner's from Px, V from LDS ----
    bf16x8 pa4[4];
    pa4[kh * 2 + 0] = *reinterpret_cast<const bf16x8*>(&f0);
    pa4[kh * 2 + 1] = *reinterpret_cast<const bf16x8*>(&f1);
    pa4[(1 - kh) * 2 + 0] = *reinterpret_cast<const bf16x8*>(px_par0);
    pa4[(1 - kh) * 2 + 1] = *reinterpret_cast<const bf16x8*>(px_par1);
    __builtin_amdgcn_s_setprio(1);
    #pragma unroll
    for (int ot = 0; ot < 4; ot++) {
      const u16* vrow = &Vs[(hh * 128 + ot * 32 + l32) * 64];
      #pragma unroll
      for (int kc2 = 0; kc2 < 4; kc2++) {
        bf16x8 vf = *reinterpret_cast<const bf16x8*>(
            &vrow[((kc2 * 2 + hi) ^ kswz) << 3]);
        o[ot] = mfma32(pa4[kc2], vf, o[ot]);
      }
    }
    __builtin_amdgcn_s_setprio(0);

    // all Vs/Px reads retired; barrier -> safe to overwrite Vs/Px
    bar();
    // ---- V DMA for kt+1: latency hidden under next QK ----
    if (kt < 15) stage_v(kt + 1);
  }

  // ---- l-sum: combine hi-halves, exchange across kh-waves via lsb ----
  lper += __shfl_xor(lper, 32, 64);
  if (lane < 32) lsb[(qh * 2 + kh) * 32 + l32] = lper;
  __syncthreads();

  float invl[16];
  #pragma unroll
  for (int r = 0; r < 16; r++) {
    int row = (r & 3) + 8 * (r >> 2) + 4 * hi;   // q within tile-half
    invl[r] = 1.0f / (lsb[qh * 64 + row] + lsb[qh * 64 + 32 + row]);
  }

  u16* Ew = &Ks[0] + wv * 1280;
  const int grow = b * 1024 + qrow0 + l32;
  #pragma unroll
  for (int ot = 0; ot < 4; ot++) {
    #pragma unroll
    for (int r = 0; r < 16; r++) {
      int row = (r & 3) + 8 * (r >> 2) + 4 * hi;
      Ew[row * 40 + l32] = f2bf(o[ot][r] * invl[r]);
    }
    int ht = hh * 4 + ot;
    uint4 v0 = *reinterpret_cast<const uint4*>(&Ew[l32 * 40 + hi * 16]);
    uint4 v1 = *reinterpret_cast<const uint4*>(&Ew[l32 * 40 + hi * 16 + 8]);
    u16* op = obuf + (((size_t)n * 8 + ht) * BT_ + grow) * 32 + hi * 16;
    *reinterpret_cast<uint4*>(op) = v0;
    *reinterpret_cast<uint4*>(op + 8) = v1;
  }
}

// ---------- K4: combine 8 branches (signed) + LayerNorm over H — wave-per-row ----------
__global__ __launch_bounds__(256) void combine_ln2_kernel(
    const u16* __restrict__ obuf, const float* __restrict__ w,
    const float* __restrict__ bi, float* __restrict__ out) {
  const int wid = threadIdx.x >> 6, lane = threadIdx.x & 63;
  const int row = blockIdx.x * 4 + wid;
  const int ht0 = lane >> 3;          // (lane*4)>>5
  const int hin = (lane & 7) * 4;     // (lane*4)&31

  float o[8][4];
  #pragma unroll
  for (int nn = 0; nn < 8; nn++) {
    const u16* p = obuf + (((size_t)(nn * 8 + ht0) * BT_ + row) * 32 + hin);
    ushort4 v = *reinterpret_cast<const ushort4*>(p);
    o[nn][0] = bf1(v.x); o[nn][1] = bf1(v.y);
    o[nn][2] = bf1(v.z); o[nn][3] = bf1(v.w);
  }
  float re[4], im[4];
  float sr = 0.f, si = 0.f, sr2 = 0.f, si2 = 0.f;
  #pragma unroll
  for (int j = 0; j < 4; j++) {
    re[j] = o[0][j] - o[1][j] - o[2][j] - o[3][j];
    im[j] = o[4][j] + o[5][j] + o[6][j] - o[7][j];
    sr += re[j]; si += im[j];
    sr2 += re[j] * re[j]; si2 += im[j] * im[j];
  }
  #pragma unroll
  for (int off = 32; off > 0; off >>= 1) {
    sr  += __shfl_xor(sr,  off, 64);
    si  += __shfl_xor(si,  off, 64);
    sr2 += __shfl_xor(sr2, off, 64);
    si2 += __shfl_xor(si2, off, 64);
  }
  const float inv = 1.0f / H_;
  float mr = sr * inv, mi = si * inv;
  float vr = sr2 * inv - mr * mr, vi = si2 * inv - mi * mi;
  float rr = rsqrtf(vr + EPS), ri = rsqrtf(vi + EPS);
  float4 w4 = *reinterpret_cast<const float4*>(w + lane * 4);
  float4 b4 = *reinterpret_cast<const float4*>(bi + lane * 4);
  const float wj[4] = {w4.x, w4.y, w4.z, w4.w};
  const float bj[4] = {b4.x, b4.y, b4.z, b4.w};
  float res[8];
  #pragma unroll
  for (int j = 0; j < 4; j++) {
    res[2 * j]     = (re[j] - mr) * rr * wj[j] + bj[j];
    res[2 * j + 1] = (im[j] - mi) * ri * wj[j] + bj[j];
  }
  float* op = out + ((size_t)row * H_ + lane * 4) * 2;
  *reinterpret_cast<float4*>(op)     = (float4){res[0], res[1], res[2], res[3]};
  *reinterpret_cast<float4*>(op + 4) = (float4){res[4], res[5], res[6], res[7]};
}

extern "C" void kernel_launch(void* const* d_in, const int* in_sizes, int n_in,
                              void* d_out, int out_size, void* d_ws, size_t ws_size,
                              hipStream_t stream) {
  const float* x    = (const float*)d_in[0];
  const float* Wq   = (const float*)d_in[1];
  const float* bq   = (const float*)d_in[2];
  const float* Wk   = (const float*)d_in[3];
  const float* bk   = (const float*)d_in[4];
  const float* Wv   = (const float*)d_in[5];
  const float* bv   = (const float*)d_in[6];
  const float* ln1w = (const float*)d_in[7];
  const float* ln1b = (const float*)d_in[8];
  const float* ln2w = (const float*)d_in[9];
  const float* ln2b = (const float*)d_in[10];

  // Workspace (128 MB), lifetime-aliased:
  //  [0,8)  xn  (dead after qkv)  |  [0,32)  obuf (written by attn, after qkv)
  //  [8,11) wT  (dead after qkv)
  //  [32,64) vT ; [64,96) q ; [96,128) k
  char* ws = (char*)d_ws;
  u16* xnr  = (u16*)(ws);
  u16* xni  = (u16*)(ws + (4ull  << 20));
  u16* wTb  = (u16*)(ws + (8ull  << 20));
  u16* obuf = (u16*)(ws);
  u16* vT   = (u16*)(ws + (32ull << 20));
  u16* qbuf = (u16*)(ws + (64ull << 20));
  u16* kbuf = (u16*)(ws + (96ull << 20));

  prologue_kernel<<<2432, 256, 0, stream>>>(x, ln1w, ln1b, xnr, xni,
                                            Wq, Wk, Wv, wTb);
  qkv_kernel<<<dim3(32, 24), 512, 0, stream>>>(xnr, xni, wTb, bq, bk, bv,
                                               qbuf, kbuf, vT);
  attn_kernel<<<dim3(16, 64), 256, 0, stream>>>(qbuf, kbuf, vT, obuf);
  combine_ln2_kernel<<<2048, 256, 0, stream>>>(obuf, ln2w, ln2b, (float*)d_out);
}

// Round 11
// 231.664 us; speedup vs baseline: 1.1717x; 1.1717x over previous
//
#include <hip/hip_runtime.h>
#include <math.h>

#define B_ 8
#define T_ 1024
#define F_ 256
#define H_ 256
#define BT_ (B_*T_)          // 8192
constexpr float EPS = 1e-5f;
constexpr float SCALE = 0.0625f;        // 1/sqrt(256), folded into qbuf

typedef unsigned int u32;
typedef unsigned short u16;
typedef __attribute__((ext_vector_type(8))) short bf16x8;    // 8 bf16 = 4 VGPRs
typedef __attribute__((ext_vector_type(4))) float f32x4;
typedef __attribute__((ext_vector_type(16))) float f32x16;

// ---------- bf16 helpers ----------
__device__ __forceinline__ float bf1(u16 p) { return __uint_as_float(((u32)p) << 16); }
__device__ __forceinline__ u16 f2bf(float f) {
  u32 u = __float_as_uint(f);
  u32 r = u + 0x7FFFu + ((u >> 16) & 1u);   // RNE
  return (u16)(r >> 16);
}

__device__ __forceinline__ f32x4 mfma16(bf16x8 a, bf16x8 b, f32x4 c) {
  return __builtin_amdgcn_mfma_f32_16x16x32_bf16(a, b, c, 0, 0, 0);
}
__device__ __forceinline__ f32x16 mfma32(bf16x8 a, bf16x8 b, f32x16 c) {
  return __builtin_amdgcn_mfma_f32_32x32x16_bf16(a, b, c, 0, 0, 0);
}

// async global->LDS, 16B per lane; dest = wave-uniform base + lane*16
__device__ __forceinline__ void gload_lds16(const u16* g, u16* l) {
  __builtin_amdgcn_global_load_lds(
      (const __attribute__((address_space(1))) u32*)(uintptr_t)g,
      (__attribute__((address_space(3))) u32*)(u32)(uintptr_t)l,
      16, 0, 0);
}

// raw barrier bracketed by sched fences (raw s_barrier does NOT drain counters)
__device__ __forceinline__ void bar() {
  __builtin_amdgcn_sched_barrier(0);
  __builtin_amdgcn_s_barrier();
  __builtin_amdgcn_sched_barrier(0);
}

// ---------- K1: fused prologue ----------
// blocks [0,2048): LayerNorm over F, wave-per-row (barrier-free, no LDS).
// blocks [2048,2432): weight prep transpose W[z][f][h] f32 -> wT[z][h][f] bf16.
__global__ __launch_bounds__(256) void prologue_kernel(
    const float* __restrict__ x, const float* __restrict__ w, const float* __restrict__ bi,
    u16* __restrict__ xnr, u16* __restrict__ xni,
    const float* __restrict__ Wq, const float* __restrict__ Wk, const float* __restrict__ Wv,
    u16* __restrict__ wT) {
  const int tid = threadIdx.x;
  if (blockIdx.x < 2048) {
    // ---- ln1: one row per wave ----
    const int wid = tid >> 6, lane = tid & 63;
    const int row = blockIdx.x * 4 + wid;
    const float2* xr = reinterpret_cast<const float2*>(x) + (size_t)row * F_;
    float2 xv[4];
    float sr = 0.f, si = 0.f, sr2 = 0.f, si2 = 0.f;
    #pragma unroll
    for (int j = 0; j < 4; j++) {
      xv[j] = xr[lane * 4 + j];
      sr += xv[j].x; si += xv[j].y;
      sr2 += xv[j].x * xv[j].x; si2 += xv[j].y * xv[j].y;
    }
    #pragma unroll
    for (int off = 32; off > 0; off >>= 1) {
      sr  += __shfl_xor(sr,  off, 64);
      si  += __shfl_xor(si,  off, 64);
      sr2 += __shfl_xor(sr2, off, 64);
      si2 += __shfl_xor(si2, off, 64);
    }
    const float inv = 1.0f / F_;
    float mr = sr * inv, mi = si * inv;
    float vr = sr2 * inv - mr * mr, vi = si2 * inv - mi * mi;
    float rr = rsqrtf(vr + EPS), ri = rsqrtf(vi + EPS);
    float4 w4 = *reinterpret_cast<const float4*>(w + lane * 4);
    float4 b4 = *reinterpret_cast<const float4*>(bi + lane * 4);
    const float wj[4] = {w4.x, w4.y, w4.z, w4.w};
    const float bj[4] = {b4.x, b4.y, b4.z, b4.w};
    ushort4 outr, outi;
    u16* orp = reinterpret_cast<u16*>(&outr);
    u16* oip = reinterpret_cast<u16*>(&outi);
    #pragma unroll
    for (int j = 0; j < 4; j++) {
      orp[j] = f2bf((xv[j].x - mr) * rr * wj[j] + bj[j]);
      oip[j] = f2bf((xv[j].y - mi) * ri * wj[j] + bj[j]);
    }
    *reinterpret_cast<ushort4*>(xnr + (size_t)row * F_ + lane * 4) = outr;
    *reinterpret_cast<ushort4*>(xni + (size_t)row * F_ + lane * 4) = outi;
  } else {
    // ---- wprep: 384 blocks, z = idx/16, 64x64 tile (ft,ht) = idx%16 ----
    const int idx = blockIdx.x - 2048;
    const int z = idx >> 4, rem = idx & 15;
    const int m = z >> 3, n = z & 7;
    const float* W = (m == 0 ? Wq : (m == 1 ? Wk : Wv)) + (size_t)n * F_ * H_;
    const int ft = (rem & 3) * 64;
    const int ht = (rem >> 2) * 64;
    __shared__ __align__(16) u16 Ts[64][72];
    #pragma unroll
    for (int i = 0; i < 4; i++) {
      int id = tid + i * 256;
      int r = id >> 4, c4 = (id & 15) * 4;
      float4 p = *reinterpret_cast<const float4*>(&W[(size_t)(ft + r) * H_ + ht + c4]);
      Ts[r][c4 + 0] = f2bf(p.x); Ts[r][c4 + 1] = f2bf(p.y);
      Ts[r][c4 + 2] = f2bf(p.z); Ts[r][c4 + 3] = f2bf(p.w);
    }
    __syncthreads();
    u16* op = wT + (size_t)z * F_ * H_ + (size_t)ht * F_ + ft;
    #pragma unroll
    for (int i = 0; i < 2; i++) {
      int id = tid + i * 256;
      int hl = id & 63, g = id >> 6;
      u16 tmp[8];
      #pragma unroll
      for (int j = 0; j < 8; j++) tmp[j] = Ts[g * 8 + j][hl];
      *reinterpret_cast<uint4*>(op + (size_t)hl * F_ + g * 8) =
          *reinterpret_cast<const uint4*>(tmp);
    }
  }
}

// ---------- K2: QKV projections — 512-thr, 256x256 tile, BK=64, 4 fat K-steps ----------
// (R8 configuration — session best)
__global__ __launch_bounds__(512, 2) void qkv_kernel(
    const u16* __restrict__ xnr, const u16* __restrict__ xni, const u16* __restrict__ wT,
    const float* __restrict__ bq, const float* __restrict__ bk, const float* __restrict__ bv,
    u16* __restrict__ qo, u16* __restrict__ ko, u16* __restrict__ vTo) {
  const int z = blockIdx.y;
  const int m = z >> 3, n = z & 7;
  int sel; const float* bias; u16* out;
  if (m == 0)      { sel = (n >> 1) & 1;  bias = bq; out = qo + (size_t)n * BT_ * H_; }
  else if (m == 1) { sel = n & 1;         bias = bk; out = ko + (size_t)n * BT_ * H_; }
  else             { sel = __popc(n) & 1; bias = bv; out = nullptr; }
  const float osc = (m == 0) ? SCALE : 1.0f;
  const u16* A = sel ? xni : xnr;
  const u16* wp = wT + (size_t)z * F_ * H_;
  bias += n * H_;
  const int rowbase = blockIdx.x * 256;

  __shared__ __align__(16) u16 Sh[65536];         // 128 KB flat
  // As[buf] = Sh + buf*16384 ; Bs[buf] = Sh + 32768 + buf*16384

  const int tid = threadIdx.x;                    // 0..511
  const int wv = tid >> 6, lane = tid & 63;
  const int quad = lane >> 4, l16 = lane & 15;
  const int wrow = wv >> 2, wcol = wv & 3;        // 2x4 wave grid; tile 128x64

  f32x4 acc[8][4];
  #pragma unroll
  for (int i = 0; i < 8; i++)
    #pragma unroll
    for (int j = 0; j < 4; j++) acc[i][j] = (f32x4){0.f, 0.f, 0.f, 0.f};

  const int r8 = tid >> 3;                        // staging row 0..63 (per instr)
  const int usw = ((tid & 7) ^ (r8 & 7)) * 8;     // source pre-swizzle (8 units/row)

  auto stage = [&](int s, int buf) {              // step s: kb = s*64
    const int kb = s * 64;
    #pragma unroll
    for (int c = 0; c < 4; c++) {
      gload_lds16(A + (size_t)(rowbase + c * 64 + r8) * F_ + kb + usw,
                  &Sh[buf * 16384 + c * 4096 + tid * 8]);
      gload_lds16(wp + (size_t)(c * 64 + r8) * F_ + kb + usw,
                  &Sh[32768 + buf * 16384 + c * 4096 + tid * 8]);
    }
  };

  stage(0, 0);
  __builtin_amdgcn_sched_barrier(0);

  const int rswb = l16 & 7;                       // read swizzle: row&7 = l16&7

  #pragma unroll 1
  for (int s = 0; s < 4; s++) {
    const int buf = s & 1;
    if (s < 3) {
      stage(s + 1, buf ^ 1);                      // 8 DMAs, stay in flight
      __builtin_amdgcn_sched_barrier(0);
      asm volatile("s_waitcnt vmcnt(8)" ::: "memory");   // drain stage(s) only
    } else {
      asm volatile("s_waitcnt vmcnt(0)" ::: "memory");
    }
    bar();                                        // all waves: buf ready

    #pragma unroll
    for (int kk = 0; kk < 2; kk++) {              // two K=32 sub-windows
      bf16x8 a[8], b[4];
      #pragma unroll
      for (int mi = 0; mi < 8; mi++) {
        int row = wrow * 128 + mi * 16 + l16;
        a[mi] = *reinterpret_cast<const bf16x8*>(
            &Sh[buf * 16384 + row * 64 + (((kk * 4 + quad) ^ rswb) << 3)]);
      }
      #pragma unroll
      for (int nj = 0; nj < 4; nj++) {
        int row = wcol * 64 + nj * 16 + l16;
        b[nj] = *reinterpret_cast<const bf16x8*>(
            &Sh[32768 + buf * 16384 + row * 64 + (((kk * 4 + quad) ^ rswb) << 3)]);
      }
      __builtin_amdgcn_s_setprio(1);
      #pragma unroll
      for (int mi = 0; mi < 8; mi++)
        #pragma unroll
        for (int nj = 0; nj < 4; nj++)
          acc[mi][nj] = mfma16(a[mi], b[nj], acc[mi][nj]);
      __builtin_amdgcn_s_setprio(0);
    }
    bar();                                        // buf reads retired -> reusable
  }

  float bias4[4];
  #pragma unroll
  for (int nj = 0; nj < 4; nj++)
    bias4[nj] = bias[wcol * 64 + nj * 16 + l16];

  if (m != 2) {   // q/k: row-major store (already coalesced along h)
    u16* Epi = Sh + wv * 1536;                    // wave-private 3KB
    #pragma unroll
    for (int mi = 0; mi < 8; mi++) {
      #pragma unroll
      for (int nj = 0; nj < 4; nj++)
        #pragma unroll
        for (int r = 0; r < 4; r++)
          Epi[(quad * 4 + r) * 72 + nj * 16 + l16] =
              f2bf((acc[mi][nj][r] + bias4[nj]) * osc);
      int row = rowbase + wrow * 128 + mi * 16 + l16;
      uint4 v0 = *reinterpret_cast<const uint4*>(&Epi[l16 * 72 + quad * 16]);
      uint4 v1 = *reinterpret_cast<const uint4*>(&Epi[l16 * 72 + quad * 16 + 8]);
      u16* op = out + (size_t)row * H_ + wcol * 64 + quad * 16;
      *reinterpret_cast<uint4*>(op) = v0;
      *reinterpret_cast<uint4*>(op + 8) = v1;
    }
  } else {        // v: [h][bt] transpose per wave, stores coalesced along bt
    u16* Epv = Sh + wv * 4608;                    // 64 x 72 u16 = 9216 B, wave-private
    #pragma unroll
    for (int hp = 0; hp < 2; hp++) {              // two 64-bt halves (mi = hp*4+mj)
      #pragma unroll
      for (int mj = 0; mj < 4; mj++)
        #pragma unroll
        for (int nj = 0; nj < 4; nj++) {
          ushort4 pv;
          u16* pp = reinterpret_cast<u16*>(&pv);
          #pragma unroll
          for (int r = 0; r < 4; r++)
            pp[r] = f2bf(acc[hp * 4 + mj][nj][r] + bias4[nj]);
          *reinterpret_cast<uint2*>(
              &Epv[(nj * 16 + l16) * 72 + mj * 16 + quad * 4]) =
              *reinterpret_cast<const uint2*>(&pv);
        }
      #pragma unroll
      for (int i = 0; i < 8; i++) {
        int hrow = i * 8 + (lane >> 3);
        uint4 vv = *reinterpret_cast<const uint4*>(
            &Epv[hrow * 72 + (lane & 7) * 8]);
        u16* op = vTo + (size_t)n * H_ * BT_ +
                  (size_t)(wcol * 64 + hrow) * BT_ +
                  rowbase + wrow * 128 + hp * 64 + (lane & 7) * 8;
        *reinterpret_cast<uint4*>(op) = vv;
      }
    }
  }
}

// ---------- K3: MFMA flash attention v3 — DMA-staged K AND V, counted-vmcnt pipeline ----------
// (R4 kernel VERBATIM — 106 µs stable, session-best attn. v2/v4/v5/v6 all regressed:
// direct-global V = latency-bound; V-in-reg = strided-L2 + outlier; wave-private V
// = wait-structure overhead; swapped-QK in-reg P = VGPR spill, WRITE_SIZE 2.3x.)
__global__ __launch_bounds__(256, 2) void attn_kernel(
    const u16* __restrict__ q, const u16* __restrict__ k, const u16* __restrict__ vT,
    u16* __restrict__ obuf) {
  // XCD-swizzled mapping: lin%8 = XCD; 16 consecutive slots per XCD = one nb.
  const int lin = blockIdx.y * 16 + blockIdx.x;   // 0..1023
  const int qt  = (lin >> 3) & 15;                // q-tile: 64 query rows
  const int nb  = (lin & 7) | ((lin >> 7) << 3);  // n*8 + b
  const int n = nb >> 3, b = nb & 7;
  const int tid = threadIdx.x;
  const int wv = tid >> 6, lane = tid & 63;
  const int hi = lane >> 5, l32 = lane & 31;
  const int qh = wv >> 1;            // q-half (32 rows)
  const int kh = wv & 1;             // QK: key-half (32 keys)
  const int hh = wv & 1;             // PV: h-half (128 h)

  const size_t base = (size_t)nb * T_ * H_;
  const u16* qp = q + base;          // pre-scaled by SCALE
  const u16* kp = k + base;
  const u16* vtp = vT + ((size_t)n * H_ * B_ + b) * T_;

  __shared__ __align__(16) u16 Ks[64 * 256];   // 32 KB, row-linear, XOR-swizzled units
  __shared__ __align__(16) u16 Vs[256 * 64];   // 32 KB, [h][key], XOR-swizzled units
  __shared__ __align__(16) u16 Ps[2][32][72];  // 9 KB; cols 64..67 hold l-sums

  const int sr = tid >> 5, su = tid & 31;      // K DMA map: 2 rows x 32 units / wave-instr

  // ---- staging helpers (DMA; source pre-swizzled, LDS linear) ----
  auto stage_k = [&](int kt) {
    #pragma unroll
    for (int i = 0; i < 8; i++) {
      int row = i * 8 + sr;
      gload_lds16(kp + (size_t)(kt * 64 + row) * H_ + ((su ^ (row & 7)) * 8),
                  &Ks[i * 2048 + tid * 8]);
    }
  };
  auto stage_v = [&](int kt) {
    #pragma unroll
    for (int i = 0; i < 8; i++) {
      int g = (wv * 8 + i) * 64 + lane;        // 16B-unit index 0..2047
      int row = g >> 3, u = g & 7;             // 8 rows x 8 units / wave-instr
      gload_lds16(vtp + (size_t)row * BT_ + kt * 64 + ((u ^ (row & 7)) * 8),
                  &Vs[g * 8]);
    }
  };

  // prologue: K0 then V0 in flight (K DMAs precede V DMAs in issue order — the
  // counted waits below rely only on that)
  stage_k(0);
  stage_v(0);

  const int qrow0 = qt * 64 + qh * 32;
  bf16x8 qf[16];
  #pragma unroll
  for (int kc = 0; kc < 16; kc++)
    qf[kc] = *reinterpret_cast<const bf16x8*>(
        qp + (size_t)(qrow0 + l32) * H_ + kc * 16 + hi * 8);

  f32x16 o[4];
  #pragma unroll
  for (int ot = 0; ot < 4; ot++)
    #pragma unroll
    for (int r = 0; r < 16; r++) o[ot][r] = 0.f;
  float lper[16];
  #pragma unroll
  for (int r = 0; r < 16; r++) lper[r] = 0.f;

  const int krow = kh * 32 + l32;
  const int kswz = l32 & 7;

  #pragma unroll 1
  for (int kt = 0; kt < 16; kt++) {
    // K(kt) landed (own 8 newest outstanding are V(kt)); barrier -> all waves' K landed
    asm volatile("s_waitcnt vmcnt(8)" ::: "memory");
    bar();

    // ---- QK^T from swizzled Ks ----
    f32x16 sa, sb;
    #pragma unroll
    for (int r = 0; r < 16; r++) { sa[r] = 0.f; sb[r] = 0.f; }
    __builtin_amdgcn_s_setprio(1);
    #pragma unroll
    for (int kc = 0; kc < 16; kc += 2) {
      bf16x8 kfa = *reinterpret_cast<const bf16x8*>(
          &Ks[(krow << 8) + ((((kc)     * 2 + hi) ^ kswz) << 3)]);
      bf16x8 kfb = *reinterpret_cast<const bf16x8*>(
          &Ks[(krow << 8) + ((((kc + 1) * 2 + hi) ^ kswz) << 3)]);
      sa = mfma32(qf[kc], kfa, sa);
      sb = mfma32(qf[kc + 1], kfb, sb);
    }
    __builtin_amdgcn_s_setprio(0);

    #pragma unroll
    for (int r = 0; r < 16; r++) {
      float p = __expf(sa[r] + sb[r]);
      lper[r] += p;
      Ps[qh][(r & 3) + 8 * (r >> 2) + 4 * hi][kh * 32 + l32] = f2bf(p);
    }
    // V(kt) landed + Ps writes drained; barrier -> Vs/Ps ready, Ks reads all retired
    asm volatile("s_waitcnt vmcnt(0) lgkmcnt(0)" ::: "memory");
    bar();

    // ---- K DMA for kt+1: latency hidden under PV ----
    if (kt < 15) stage_k(kt + 1);

    // ---- PV: P and V from LDS ----
    bf16x8 pa[4];
    #pragma unroll
    for (int kc2 = 0; kc2 < 4; kc2++)
      pa[kc2] = *reinterpret_cast<const bf16x8*>(
          &Ps[qh][l32][kc2 * 16 + hi * 8]);
    __builtin_amdgcn_s_setprio(1);
    #pragma unroll
    for (int ot = 0; ot < 4; ot++) {
      const u16* vrow = &Vs[(hh * 128 + ot * 32 + l32) * 64];
      #pragma unroll
      for (int kc2 = 0; kc2 < 4; kc2++) {
        bf16x8 vf = *reinterpret_cast<const bf16x8*>(
            &vrow[((kc2 * 2 + hi) ^ kswz) << 3]);
        o[ot] = mfma32(pa[kc2], vf, o[ot]);
      }
    }
    __builtin_amdgcn_s_setprio(0);

    // all Vs/Ps reads retired; barrier -> safe to overwrite Vs
    bar();
    // ---- V DMA for kt+1: latency hidden under next QK ----
    if (kt < 15) stage_v(kt + 1);
  }

  #pragma unroll
  for (int r = 0; r < 16; r++) {
    #pragma unroll
    for (int off = 1; off < 32; off <<= 1)
      lper[r] += __shfl_xor(lper[r], off, 64);
  }
  if (l32 == 0) {
    #pragma unroll
    for (int r = 0; r < 16; r++) {
      int row = (r & 3) + 8 * (r >> 2) + 4 * hi;
      *reinterpret_cast<float*>(&Ps[qh][row][64 + 2 * kh]) = lper[r];
    }
  }
  __syncthreads();

  float invl[16];
  #pragma unroll
  for (int r = 0; r < 16; r++) {
    int row = (r & 3) + 8 * (r >> 2) + 4 * hi;
    float l0 = *reinterpret_cast<const float*>(&Ps[qh][row][64]);
    float l1 = *reinterpret_cast<const float*>(&Ps[qh][row][66]);
    invl[r] = 1.0f / (l0 + l1);
  }

  u16* Ew = &Ks[0] + wv * 1280;
  const int grow = b * 1024 + qrow0 + l32;
  #pragma unroll
  for (int ot = 0; ot < 4; ot++) {
    #pragma unroll
    for (int r = 0; r < 16; r++) {
      int row = (r & 3) + 8 * (r >> 2) + 4 * hi;
      Ew[row * 40 + l32] = f2bf(o[ot][r] * invl[r]);
    }
    int ht = hh * 4 + ot;
    uint4 v0 = *reinterpret_cast<const uint4*>(&Ew[l32 * 40 + hi * 16]);
    uint4 v1 = *reinterpret_cast<const uint4*>(&Ew[l32 * 40 + hi * 16 + 8]);
    u16* op = obuf + (((size_t)n * 8 + ht) * BT_ + grow) * 32 + hi * 16;
    *reinterpret_cast<uint4*>(op) = v0;
    *reinterpret_cast<uint4*>(op + 8) = v1;
  }
}

// ---------- K4: combine 8 branches (signed) + LayerNorm over H — wave-per-row ----------
__global__ __launch_bounds__(256) void combine_ln2_kernel(
    const u16* __restrict__ obuf, const float* __restrict__ w,
    const float* __restrict__ bi, float* __restrict__ out) {
  const int wid = threadIdx.x >> 6, lane = threadIdx.x & 63;
  const int row = blockIdx.x * 4 + wid;
  const int ht0 = lane >> 3;          // (lane*4)>>5
  const int hin = (lane & 7) * 4;     // (lane*4)&31

  float o[8][4];
  #pragma unroll
  for (int nn = 0; nn < 8; nn++) {
    const u16* p = obuf + (((size_t)(nn * 8 + ht0) * BT_ + row) * 32 + hin);
    ushort4 v = *reinterpret_cast<const ushort4*>(p);
    o[nn][0] = bf1(v.x); o[nn][1] = bf1(v.y);
    o[nn][2] = bf1(v.z); o[nn][3] = bf1(v.w);
  }
  float re[4], im[4];
  float sr = 0.f, si = 0.f, sr2 = 0.f, si2 = 0.f;
  #pragma unroll
  for (int j = 0; j < 4; j++) {
    re[j] = o[0][j] - o[1][j] - o[2][j] - o[3][j];
    im[j] = o[4][j] + o[5][j] + o[6][j] - o[7][j];
    sr += re[j]; si += im[j];
    sr2 += re[j] * re[j]; si2 += im[j] * im[j];
  }
  #pragma unroll
  for (int off = 32; off > 0; off >>= 1) {
    sr  += __shfl_xor(sr,  off, 64);
    si  += __shfl_xor(si,  off, 64);
    sr2 += __shfl_xor(sr2, off, 64);
    si2 += __shfl_xor(si2, off, 64);
  }
  const float inv = 1.0f / H_;
  float mr = sr * inv, mi = si * inv;
  float vr = sr2 * inv - mr * mr, vi = si2 * inv - mi * mi;
  float rr = rsqrtf(vr + EPS), ri = rsqrtf(vi + EPS);
  float4 w4 = *reinterpret_cast<const float4*>(w + lane * 4);
  float4 b4 = *reinterpret_cast<const float4*>(bi + lane * 4);
  const float wj[4] = {w4.x, w4.y, w4.z, w4.w};
  const float bj[4] = {b4.x, b4.y, b4.z, b4.w};
  float res[8];
  #pragma unroll
  for (int j = 0; j < 4; j++) {
    res[2 * j]     = (re[j] - mr) * rr * wj[j] + bj[j];
    res[2 * j + 1] = (im[j] - mi) * ri * wj[j] + bj[j];
  }
  float* op = out + ((size_t)row * H_ + lane * 4) * 2;
  *reinterpret_cast<float4*>(op)     = (float4){res[0], res[1], res[2], res[3]};
  *reinterpret_cast<float4*>(op + 4) = (float4){res[4], res[5], res[6], res[7]};
}

extern "C" void kernel_launch(void* const* d_in, const int* in_sizes, int n_in,
                              void* d_out, int out_size, void* d_ws, size_t ws_size,
                              hipStream_t stream) {
  const float* x    = (const float*)d_in[0];
  const float* Wq   = (const float*)d_in[1];
  const float* bq   = (const float*)d_in[2];
  const float* Wk   = (const float*)d_in[3];
  const float* bk   = (const float*)d_in[4];
  const float* Wv   = (const float*)d_in[5];
  const float* bv   = (const float*)d_in[6];
  const float* ln1w = (const float*)d_in[7];
  const float* ln1b = (const float*)d_in[8];
  const float* ln2w = (const float*)d_in[9];
  const float* ln2b = (const float*)d_in[10];

  // Workspace (128 MB), lifetime-aliased:
  //  [0,8)  xn  (dead after qkv)  |  [0,32)  obuf (written by attn, after qkv)
  //  [8,11) wT  (dead after qkv)
  //  [32,64) vT ; [64,96) q ; [96,128) k
  char* ws = (char*)d_ws;
  u16* xnr  = (u16*)(ws);
  u16* xni  = (u16*)(ws + (4ull  << 20));
  u16* wTb  = (u16*)(ws + (8ull  << 20));
  u16* obuf = (u16*)(ws);
  u16* vT   = (u16*)(ws + (32ull << 20));
  u16* qbuf = (u16*)(ws + (64ull << 20));
  u16* kbuf = (u16*)(ws + (96ull << 20));

  prologue_kernel<<<2432, 256, 0, stream>>>(x, ln1w, ln1b, xnr, xni,
                                            Wq, Wk, Wv, wTb);
  qkv_kernel<<<dim3(32, 24), 512, 0, stream>>>(xnr, xni, wTb, bq, bk, bv,
                                               qbuf, kbuf, vT);
  attn_kernel<<<dim3(16, 64), 256, 0, stream>>>(qbuf, kbuf, vT, obuf);
  combine_ln2_kernel<<<2048, 256, 0, stream>>>(obuf, ln2w, ln2b, (float*)d_out);
}

// Round 12
// 224.329 us; speedup vs baseline: 1.2100x; 1.0327x over previous
//
#include <hip/hip_runtime.h>
#include <math.h>

#define B_ 8
#define T_ 1024
#define F_ 256
#define H_ 256
#define BT_ (B_*T_)          // 8192
constexpr float EPS = 1e-5f;
constexpr float SCALE = 0.0625f;        // 1/sqrt(256), folded into qbuf

typedef unsigned int u32;
typedef unsigned short u16;
typedef __attribute__((ext_vector_type(8))) short bf16x8;    // 8 bf16 = 4 VGPRs
typedef __attribute__((ext_vector_type(4))) float f32x4;
typedef __attribute__((ext_vector_type(16))) float f32x16;

// ---------- bf16 helpers ----------
__device__ __forceinline__ float bf1(u16 p) { return __uint_as_float(((u32)p) << 16); }
__device__ __forceinline__ u16 f2bf(float f) {
  u32 u = __float_as_uint(f);
  u32 r = u + 0x7FFFu + ((u >> 16) & 1u);   // RNE
  return (u16)(r >> 16);
}

__device__ __forceinline__ f32x4 mfma16(bf16x8 a, bf16x8 b, f32x4 c) {
  return __builtin_amdgcn_mfma_f32_16x16x32_bf16(a, b, c, 0, 0, 0);
}
__device__ __forceinline__ f32x16 mfma32(bf16x8 a, bf16x8 b, f32x16 c) {
  return __builtin_amdgcn_mfma_f32_32x32x16_bf16(a, b, c, 0, 0, 0);
}

// async global->LDS, 16B per lane; dest = wave-uniform base + lane*16
__device__ __forceinline__ void gload_lds16(const u16* g, u16* l) {
  __builtin_amdgcn_global_load_lds(
      (const __attribute__((address_space(1))) u32*)(uintptr_t)g,
      (__attribute__((address_space(3))) u32*)(u32)(uintptr_t)l,
      16, 0, 0);
}

// raw barrier bracketed by sched fences (raw s_barrier does NOT drain counters)
__device__ __forceinline__ void bar() {
  __builtin_amdgcn_sched_barrier(0);
  __builtin_amdgcn_s_barrier();
  __builtin_amdgcn_sched_barrier(0);
}

// ---------- K1: fused prologue ----------
// blocks [0,2048): LayerNorm over F, wave-per-row (barrier-free, no LDS).
// blocks [2048,2432): weight prep transpose W[z][f][h] f32 -> wT[z][h][f] bf16.
__global__ __launch_bounds__(256) void prologue_kernel(
    const float* __restrict__ x, const float* __restrict__ w, const float* __restrict__ bi,
    u16* __restrict__ xnr, u16* __restrict__ xni,
    const float* __restrict__ Wq, const float* __restrict__ Wk, const float* __restrict__ Wv,
    u16* __restrict__ wT) {
  const int tid = threadIdx.x;
  if (blockIdx.x < 2048) {
    // ---- ln1: one row per wave ----
    const int wid = tid >> 6, lane = tid & 63;
    const int row = blockIdx.x * 4 + wid;
    const float2* xr = reinterpret_cast<const float2*>(x) + (size_t)row * F_;
    float2 xv[4];
    float sr = 0.f, si = 0.f, sr2 = 0.f, si2 = 0.f;
    #pragma unroll
    for (int j = 0; j < 4; j++) {
      xv[j] = xr[lane * 4 + j];
      sr += xv[j].x; si += xv[j].y;
      sr2 += xv[j].x * xv[j].x; si2 += xv[j].y * xv[j].y;
    }
    #pragma unroll
    for (int off = 32; off > 0; off >>= 1) {
      sr  += __shfl_xor(sr,  off, 64);
      si  += __shfl_xor(si,  off, 64);
      sr2 += __shfl_xor(sr2, off, 64);
      si2 += __shfl_xor(si2, off, 64);
    }
    const float inv = 1.0f / F_;
    float mr = sr * inv, mi = si * inv;
    float vr = sr2 * inv - mr * mr, vi = si2 * inv - mi * mi;
    float rr = rsqrtf(vr + EPS), ri = rsqrtf(vi + EPS);
    float4 w4 = *reinterpret_cast<const float4*>(w + lane * 4);
    float4 b4 = *reinterpret_cast<const float4*>(bi + lane * 4);
    const float wj[4] = {w4.x, w4.y, w4.z, w4.w};
    const float bj[4] = {b4.x, b4.y, b4.z, b4.w};
    ushort4 outr, outi;
    u16* orp = reinterpret_cast<u16*>(&outr);
    u16* oip = reinterpret_cast<u16*>(&outi);
    #pragma unroll
    for (int j = 0; j < 4; j++) {
      orp[j] = f2bf((xv[j].x - mr) * rr * wj[j] + bj[j]);
      oip[j] = f2bf((xv[j].y - mi) * ri * wj[j] + bj[j]);
    }
    *reinterpret_cast<ushort4*>(xnr + (size_t)row * F_ + lane * 4) = outr;
    *reinterpret_cast<ushort4*>(xni + (size_t)row * F_ + lane * 4) = outi;
  } else {
    // ---- wprep: 384 blocks, z = idx/16, 64x64 tile (ft,ht) = idx%16 ----
    const int idx = blockIdx.x - 2048;
    const int z = idx >> 4, rem = idx & 15;
    const int m = z >> 3, n = z & 7;
    const float* W = (m == 0 ? Wq : (m == 1 ? Wk : Wv)) + (size_t)n * F_ * H_;
    const int ft = (rem & 3) * 64;
    const int ht = (rem >> 2) * 64;
    __shared__ __align__(16) u16 Ts[64][72];
    #pragma unroll
    for (int i = 0; i < 4; i++) {
      int id = tid + i * 256;
      int r = id >> 4, c4 = (id & 15) * 4;
      float4 p = *reinterpret_cast<const float4*>(&W[(size_t)(ft + r) * H_ + ht + c4]);
      Ts[r][c4 + 0] = f2bf(p.x); Ts[r][c4 + 1] = f2bf(p.y);
      Ts[r][c4 + 2] = f2bf(p.z); Ts[r][c4 + 3] = f2bf(p.w);
    }
    __syncthreads();
    u16* op = wT + (size_t)z * F_ * H_ + (size_t)ht * F_ + ft;
    #pragma unroll
    for (int i = 0; i < 2; i++) {
      int id = tid + i * 256;
      int hl = id & 63, g = id >> 6;
      u16 tmp[8];
      #pragma unroll
      for (int j = 0; j < 8; j++) tmp[j] = Ts[g * 8 + j][hl];
      *reinterpret_cast<uint4*>(op + (size_t)hl * F_ + g * 8) =
          *reinterpret_cast<const uint4*>(tmp);
    }
  }
}

// ---------- K2: QKV projections — 512-thr, 256x256 tile, BK=64, 4 fat K-steps ----------
// (R8 configuration — session best)
__global__ __launch_bounds__(512, 2) void qkv_kernel(
    const u16* __restrict__ xnr, const u16* __restrict__ xni, const u16* __restrict__ wT,
    const float* __restrict__ bq, const float* __restrict__ bk, const float* __restrict__ bv,
    u16* __restrict__ qo, u16* __restrict__ ko, u16* __restrict__ vTo) {
  const int z = blockIdx.y;
  const int m = z >> 3, n = z & 7;
  int sel; const float* bias; u16* out;
  if (m == 0)      { sel = (n >> 1) & 1;  bias = bq; out = qo + (size_t)n * BT_ * H_; }
  else if (m == 1) { sel = n & 1;         bias = bk; out = ko + (size_t)n * BT_ * H_; }
  else             { sel = __popc(n) & 1; bias = bv; out = nullptr; }
  const float osc = (m == 0) ? SCALE : 1.0f;
  const u16* A = sel ? xni : xnr;
  const u16* wp = wT + (size_t)z * F_ * H_;
  bias += n * H_;
  const int rowbase = blockIdx.x * 256;

  __shared__ __align__(16) u16 Sh[65536];         // 128 KB flat
  // As[buf] = Sh + buf*16384 ; Bs[buf] = Sh + 32768 + buf*16384

  const int tid = threadIdx.x;                    // 0..511
  const int wv = tid >> 6, lane = tid & 63;
  const int quad = lane >> 4, l16 = lane & 15;
  const int wrow = wv >> 2, wcol = wv & 3;        // 2x4 wave grid; tile 128x64

  f32x4 acc[8][4];
  #pragma unroll
  for (int i = 0; i < 8; i++)
    #pragma unroll
    for (int j = 0; j < 4; j++) acc[i][j] = (f32x4){0.f, 0.f, 0.f, 0.f};

  const int r8 = tid >> 3;                        // staging row 0..63 (per instr)
  const int usw = ((tid & 7) ^ (r8 & 7)) * 8;     // source pre-swizzle (8 units/row)

  auto stage = [&](int s, int buf) {              // step s: kb = s*64
    const int kb = s * 64;
    #pragma unroll
    for (int c = 0; c < 4; c++) {
      gload_lds16(A + (size_t)(rowbase + c * 64 + r8) * F_ + kb + usw,
                  &Sh[buf * 16384 + c * 4096 + tid * 8]);
      gload_lds16(wp + (size_t)(c * 64 + r8) * F_ + kb + usw,
                  &Sh[32768 + buf * 16384 + c * 4096 + tid * 8]);
    }
  };

  stage(0, 0);
  __builtin_amdgcn_sched_barrier(0);

  const int rswb = l16 & 7;                       // read swizzle: row&7 = l16&7

  #pragma unroll 1
  for (int s = 0; s < 4; s++) {
    const int buf = s & 1;
    if (s < 3) {
      stage(s + 1, buf ^ 1);                      // 8 DMAs, stay in flight
      __builtin_amdgcn_sched_barrier(0);
      asm volatile("s_waitcnt vmcnt(8)" ::: "memory");   // drain stage(s) only
    } else {
      asm volatile("s_waitcnt vmcnt(0)" ::: "memory");
    }
    bar();                                        // all waves: buf ready

    #pragma unroll
    for (int kk = 0; kk < 2; kk++) {              // two K=32 sub-windows
      bf16x8 a[8], b[4];
      #pragma unroll
      for (int mi = 0; mi < 8; mi++) {
        int row = wrow * 128 + mi * 16 + l16;
        a[mi] = *reinterpret_cast<const bf16x8*>(
            &Sh[buf * 16384 + row * 64 + (((kk * 4 + quad) ^ rswb) << 3)]);
      }
      #pragma unroll
      for (int nj = 0; nj < 4; nj++) {
        int row = wcol * 64 + nj * 16 + l16;
        b[nj] = *reinterpret_cast<const bf16x8*>(
            &Sh[32768 + buf * 16384 + row * 64 + (((kk * 4 + quad) ^ rswb) << 3)]);
      }
      __builtin_amdgcn_s_setprio(1);
      #pragma unroll
      for (int mi = 0; mi < 8; mi++)
        #pragma unroll
        for (int nj = 0; nj < 4; nj++)
          acc[mi][nj] = mfma16(a[mi], b[nj], acc[mi][nj]);
      __builtin_amdgcn_s_setprio(0);
    }
    bar();                                        // buf reads retired -> reusable
  }

  float bias4[4];
  #pragma unroll
  for (int nj = 0; nj < 4; nj++)
    bias4[nj] = bias[wcol * 64 + nj * 16 + l16];

  if (m != 2) {   // q/k: row-major store (already coalesced along h)
    u16* Epi = Sh + wv * 1536;                    // wave-private 3KB
    #pragma unroll
    for (int mi = 0; mi < 8; mi++) {
      #pragma unroll
      for (int nj = 0; nj < 4; nj++)
        #pragma unroll
        for (int r = 0; r < 4; r++)
          Epi[(quad * 4 + r) * 72 + nj * 16 + l16] =
              f2bf((acc[mi][nj][r] + bias4[nj]) * osc);
      int row = rowbase + wrow * 128 + mi * 16 + l16;
      uint4 v0 = *reinterpret_cast<const uint4*>(&Epi[l16 * 72 + quad * 16]);
      uint4 v1 = *reinterpret_cast<const uint4*>(&Epi[l16 * 72 + quad * 16 + 8]);
      u16* op = out + (size_t)row * H_ + wcol * 64 + quad * 16;
      *reinterpret_cast<uint4*>(op) = v0;
      *reinterpret_cast<uint4*>(op + 8) = v1;
    }
  } else {        // v: [h][bt] transpose per wave, stores coalesced along bt
    u16* Epv = Sh + wv * 4608;                    // 64 x 72 u16 = 9216 B, wave-private
    #pragma unroll
    for (int hp = 0; hp < 2; hp++) {              // two 64-bt halves (mi = hp*4+mj)
      #pragma unroll
      for (int mj = 0; mj < 4; mj++)
        #pragma unroll
        for (int nj = 0; nj < 4; nj++) {
          ushort4 pv;
          u16* pp = reinterpret_cast<u16*>(&pv);
          #pragma unroll
          for (int r = 0; r < 4; r++)
            pp[r] = f2bf(acc[hp * 4 + mj][nj][r] + bias4[nj]);
          *reinterpret_cast<uint2*>(
              &Epv[(nj * 16 + l16) * 72 + mj * 16 + quad * 4]) =
              *reinterpret_cast<const uint2*>(&pv);
        }
      #pragma unroll
      for (int i = 0; i < 8; i++) {
        int hrow = i * 8 + (lane >> 3);
        uint4 vv = *reinterpret_cast<const uint4*>(
            &Epv[hrow * 72 + (lane & 7) * 8]);
        u16* op = vTo + (size_t)n * H_ * BT_ +
                  (size_t)(wcol * 64 + hrow) * BT_ +
                  rowbase + wrow * 128 + hp * 64 + (lane & 7) * 8;
        *reinterpret_cast<uint4*>(op) = vv;
      }
    }
  }
}

// ---------- K3: MFMA flash attention v7 — two q-tile groups share staged K/V ----------
// v3's EXACT 3-barrier counted-vmcnt scheme (verified 106 µs), widened to 512
// threads: waves 0-3 = q-tile A, waves 4-7 = q-tile B (each group runs the v3
// role split on its own 64 q-rows). Each staged Ks/Vs tile now serves 128 q-rows:
//  * staged LDS-DMA bytes per unit work HALVE (1 GB -> 512 MB over the kernel)
//  * K/V L2->HBM block-fetches halve (FETCH predicted 49 -> ~41 MB)
//  * per-wave waits scale 8->4: prologue 4K+4V; vmcnt(4) at top = K(kt) landed,
//    V(kt) in flight; vmcnt(0)+lgkm(0) mid; stage_k/v(kt+1) after b2/b3.
// LDS 84 KB -> 1 block/CU x 8 waves = same 8 waves/CU as the 2-block config.
// Risk (stated): losing inter-block phase overlap; if attn >110 µs, revert to R11.
__global__ __launch_bounds__(512, 2) void attn_kernel(
    const u16* __restrict__ q, const u16* __restrict__ k, const u16* __restrict__ vT,
    u16* __restrict__ obuf) {
  // XCD-swizzled mapping: lin%8 = XCD; 8 consecutive slots per XCD = one nb.
  const int lin = blockIdx.y * 8 + blockIdx.x;    // 0..511
  const int qst = (lin >> 3) & 7;                 // q-super-tile: 128 query rows
  const int nb  = (lin & 7) | ((lin >> 6) << 3);  // n*8 + b
  const int n = nb >> 3, b = nb & 7;
  const int tid = threadIdx.x;                    // 0..511
  const int wv = tid >> 6, lane = tid & 63;
  const int hi = lane >> 5, l32 = lane & 31;
  const int grp = wv >> 2;           // q-tile group (64 rows each)
  const int wv4 = wv & 3;
  const int qh = wv4 >> 1;           // q-half within group (32 rows)
  const int kh = wv4 & 1;            // QK: key-half (32 keys)
  const int hh = wv4 & 1;            // PV: h-half (128 h)

  const size_t base = (size_t)nb * T_ * H_;
  const u16* qp = q + base;          // pre-scaled by SCALE
  const u16* kp = k + base;
  const u16* vtp = vT + ((size_t)n * H_ * B_ + b) * T_;

  __shared__ __align__(16) u16 Ks[64 * 256];      // 32 KB, XOR-swizzled units
  __shared__ __align__(16) u16 Vs[256 * 64];      // 32 KB, [h][key], XOR-swizzled
  __shared__ __align__(16) u16 Ps[2][2][32][72];  // 18 KB: [grp][qh]; cols 64..67 l-sums

  // ---- staging (512 threads: 4 instrs each for K and V) ----
  auto stage_k = [&](int kt) {
    #pragma unroll
    for (int i = 0; i < 4; i++) {
      int row = i * 16 + (tid >> 5);             // 2048 16B-units, 32/row
      gload_lds16(kp + (size_t)(kt * 64 + row) * H_ + (((tid & 31) ^ (row & 7)) * 8),
                  &Ks[i * 4096 + tid * 8]);
    }
  };
  auto stage_v = [&](int kt) {
    #pragma unroll
    for (int i = 0; i < 4; i++) {
      int g = i * 512 + tid;                     // 16B-unit index 0..2047
      int row = g >> 3, u = g & 7;
      gload_lds16(vtp + (size_t)row * BT_ + kt * 64 + ((u ^ (row & 7)) * 8),
                  &Vs[g * 8]);
    }
  };

  // prologue: K0 (4) then V0 (4) in flight; counted waits rely on issue order
  stage_k(0);
  stage_v(0);

  const int qrow0 = qst * 128 + grp * 64 + qh * 32;
  bf16x8 qf[16];
  #pragma unroll
  for (int kc = 0; kc < 16; kc++)
    qf[kc] = *reinterpret_cast<const bf16x8*>(
        qp + (size_t)(qrow0 + l32) * H_ + kc * 16 + hi * 8);

  f32x16 o[4];
  #pragma unroll
  for (int ot = 0; ot < 4; ot++)
    #pragma unroll
    for (int r = 0; r < 16; r++) o[ot][r] = 0.f;
  float lper[16];
  #pragma unroll
  for (int r = 0; r < 16; r++) lper[r] = 0.f;

  const int krow = kh * 32 + l32;
  const int kswz = l32 & 7;

  #pragma unroll 1
  for (int kt = 0; kt < 16; kt++) {
    // K(kt) landed (own 4 newest outstanding are V(kt)); barrier -> all waves' K in
    asm volatile("s_waitcnt vmcnt(4)" ::: "memory");
    bar();

    // ---- QK^T from swizzled Ks ----
    f32x16 sa, sb;
    #pragma unroll
    for (int r = 0; r < 16; r++) { sa[r] = 0.f; sb[r] = 0.f; }
    __builtin_amdgcn_s_setprio(1);
    #pragma unroll
    for (int kc = 0; kc < 16; kc += 2) {
      bf16x8 kfa = *reinterpret_cast<const bf16x8*>(
          &Ks[(krow << 8) + ((((kc)     * 2 + hi) ^ kswz) << 3)]);
      bf16x8 kfb = *reinterpret_cast<const bf16x8*>(
          &Ks[(krow << 8) + ((((kc + 1) * 2 + hi) ^ kswz) << 3)]);
      sa = mfma32(qf[kc], kfa, sa);
      sb = mfma32(qf[kc + 1], kfb, sb);
    }
    __builtin_amdgcn_s_setprio(0);

    #pragma unroll
    for (int r = 0; r < 16; r++) {
      float p = __expf(sa[r] + sb[r]);
      lper[r] += p;
      Ps[grp][qh][(r & 3) + 8 * (r >> 2) + 4 * hi][kh * 32 + l32] = f2bf(p);
    }
    // V(kt) landed + Ps writes drained; barrier -> Vs/Ps ready, Ks reads retired
    asm volatile("s_waitcnt vmcnt(0) lgkmcnt(0)" ::: "memory");
    bar();

    // ---- K DMA for kt+1: latency hidden under PV ----
    if (kt < 15) stage_k(kt + 1);

    // ---- PV: P and V from LDS ----
    bf16x8 pa[4];
    #pragma unroll
    for (int kc2 = 0; kc2 < 4; kc2++)
      pa[kc2] = *reinterpret_cast<const bf16x8*>(
          &Ps[grp][qh][l32][kc2 * 16 + hi * 8]);
    __builtin_amdgcn_s_setprio(1);
    #pragma unroll
    for (int ot = 0; ot < 4; ot++) {
      const u16* vrow = &Vs[(hh * 128 + ot * 32 + l32) * 64];
      #pragma unroll
      for (int kc2 = 0; kc2 < 4; kc2++) {
        bf16x8 vf = *reinterpret_cast<const bf16x8*>(
            &vrow[((kc2 * 2 + hi) ^ kswz) << 3]);
        o[ot] = mfma32(pa[kc2], vf, o[ot]);
      }
    }
    __builtin_amdgcn_s_setprio(0);

    // all Vs/Ps reads retired; barrier -> safe to overwrite Vs
    bar();
    // ---- V DMA for kt+1: latency hidden under next QK ----
    if (kt < 15) stage_v(kt + 1);
  }

  #pragma unroll
  for (int r = 0; r < 16; r++) {
    #pragma unroll
    for (int off = 1; off < 32; off <<= 1)
      lper[r] += __shfl_xor(lper[r], off, 64);
  }
  if (l32 == 0) {
    #pragma unroll
    for (int r = 0; r < 16; r++) {
      int row = (r & 3) + 8 * (r >> 2) + 4 * hi;
      *reinterpret_cast<float*>(&Ps[grp][qh][row][64 + 2 * kh]) = lper[r];
    }
  }
  __syncthreads();

  float invl[16];
  #pragma unroll
  for (int r = 0; r < 16; r++) {
    int row = (r & 3) + 8 * (r >> 2) + 4 * hi;
    float l0 = *reinterpret_cast<const float*>(&Ps[grp][qh][row][64]);
    float l1 = *reinterpret_cast<const float*>(&Ps[grp][qh][row][66]);
    invl[r] = 1.0f / (l0 + l1);
  }

  u16* Ew = &Ks[0] + wv * 1280;        // 8 waves x 2560 B = 20 KB <= Ks
  const int grow = b * 1024 + qrow0 + l32;
  #pragma unroll
  for (int ot = 0; ot < 4; ot++) {
    #pragma unroll
    for (int r = 0; r < 16; r++) {
      int row = (r & 3) + 8 * (r >> 2) + 4 * hi;
      Ew[row * 40 + l32] = f2bf(o[ot][r] * invl[r]);
    }
    int ht = hh * 4 + ot;
    uint4 v0 = *reinterpret_cast<const uint4*>(&Ew[l32 * 40 + hi * 16]);
    uint4 v1 = *reinterpret_cast<const uint4*>(&Ew[l32 * 40 + hi * 16 + 8]);
    u16* op = obuf + (((size_t)n * 8 + ht) * BT_ + grow) * 32 + hi * 16;
    *reinterpret_cast<uint4*>(op) = v0;
    *reinterpret_cast<uint4*>(op + 8) = v1;
  }
}

// ---------- K4: combine 8 branches (signed) + LayerNorm over H — wave-per-row ----------
__global__ __launch_bounds__(256) void combine_ln2_kernel(
    const u16* __restrict__ obuf, const float* __restrict__ w,
    const float* __restrict__ bi, float* __restrict__ out) {
  const int wid = threadIdx.x >> 6, lane = threadIdx.x & 63;
  const int row = blockIdx.x * 4 + wid;
  const int ht0 = lane >> 3;          // (lane*4)>>5
  const int hin = (lane & 7) * 4;     // (lane*4)&31

  float o[8][4];
  #pragma unroll
  for (int nn = 0; nn < 8; nn++) {
    const u16* p = obuf + (((size_t)(nn * 8 + ht0) * BT_ + row) * 32 + hin);
    ushort4 v = *reinterpret_cast<const ushort4*>(p);
    o[nn][0] = bf1(v.x); o[nn][1] = bf1(v.y);
    o[nn][2] = bf1(v.z); o[nn][3] = bf1(v.w);
  }
  float re[4], im[4];
  float sr = 0.f, si = 0.f, sr2 = 0.f, si2 = 0.f;
  #pragma unroll
  for (int j = 0; j < 4; j++) {
    re[j] = o[0][j] - o[1][j] - o[2][j] - o[3][j];
    im[j] = o[4][j] + o[5][j] + o[6][j] - o[7][j];
    sr += re[j]; si += im[j];
    sr2 += re[j] * re[j]; si2 += im[j] * im[j];
  }
  #pragma unroll
  for (int off = 32; off > 0; off >>= 1) {
    sr  += __shfl_xor(sr,  off, 64);
    si  += __shfl_xor(si,  off, 64);
    sr2 += __shfl_xor(sr2, off, 64);
    si2 += __shfl_xor(si2, off, 64);
  }
  const float inv = 1.0f / H_;
  float mr = sr * inv, mi = si * inv;
  float vr = sr2 * inv - mr * mr, vi = si2 * inv - mi * mi;
  float rr = rsqrtf(vr + EPS), ri = rsqrtf(vi + EPS);
  float4 w4 = *reinterpret_cast<const float4*>(w + lane * 4);
  float4 b4 = *reinterpret_cast<const float4*>(bi + lane * 4);
  const float wj[4] = {w4.x, w4.y, w4.z, w4.w};
  const float bj[4] = {b4.x, b4.y, b4.z, b4.w};
  float res[8];
  #pragma unroll
  for (int j = 0; j < 4; j++) {
    res[2 * j]     = (re[j] - mr) * rr * wj[j] + bj[j];
    res[2 * j + 1] = (im[j] - mi) * ri * wj[j] + bj[j];
  }
  float* op = out + ((size_t)row * H_ + lane * 4) * 2;
  *reinterpret_cast<float4*>(op)     = (float4){res[0], res[1], res[2], res[3]};
  *reinterpret_cast<float4*>(op + 4) = (float4){res[4], res[5], res[6], res[7]};
}

extern "C" void kernel_launch(void* const* d_in, const int* in_sizes, int n_in,
                              void* d_out, int out_size, void* d_ws, size_t ws_size,
                              hipStream_t stream) {
  const float* x    = (const float*)d_in[0];
  const float* Wq   = (const float*)d_in[1];
  const float* bq   = (const float*)d_in[2];
  const float* Wk   = (const float*)d_in[3];
  const float* bk   = (const float*)d_in[4];
  const float* Wv   = (const float*)d_in[5];
  const float* bv   = (const float*)d_in[6];
  const float* ln1w = (const float*)d_in[7];
  const float* ln1b = (const float*)d_in[8];
  const float* ln2w = (const float*)d_in[9];
  const float* ln2b = (const float*)d_in[10];

  // Workspace (128 MB), lifetime-aliased:
  //  [0,8)  xn  (dead after qkv)  |  [0,32)  obuf (written by attn, after qkv)
  //  [8,11) wT  (dead after qkv)
  //  [32,64) vT ; [64,96) q ; [96,128) k
  char* ws = (char*)d_ws;
  u16* xnr  = (u16*)(ws);
  u16* xni  = (u16*)(ws + (4ull  << 20));
  u16* wTb  = (u16*)(ws + (8ull  << 20));
  u16* obuf = (u16*)(ws);
  u16* vT   = (u16*)(ws + (32ull << 20));
  u16* qbuf = (u16*)(ws + (64ull << 20));
  u16* kbuf = (u16*)(ws + (96ull << 20));

  prologue_kernel<<<2432, 256, 0, stream>>>(x, ln1w, ln1b, xnr, xni,
                                            Wq, Wk, Wv, wTb);
  qkv_kernel<<<dim3(32, 24), 512, 0, stream>>>(xnr, xni, wTb, bq, bk, bv,
                                               qbuf, kbuf, vT);
  attn_kernel<<<dim3(8, 64), 512, 0, stream>>>(qbuf, kbuf, vT, obuf);
  combine_ln2_kernel<<<2048, 256, 0, stream>>>(obuf, ln2w, ln2b, (float*)d_out);
}